// Round 7
// baseline (65.348 us; speedup 1.0000x reference)
//
#include <hip/hip_runtime.h>
#include <hip/hip_bf16.h>
#include <math.h>

#define HALF_LOG_2PI 0.9189385332046727f
#define WIN 32.0f
#define TILE_T 16

typedef float f32x4 __attribute__((ext_vector_type(4)));

// ---------------------------------------------------------------------------
// Kernel 1: fused prep + denom. Grid (Tout/256, B), 256 threads.
// Each block redundantly rebuilds its batch row's token state in LDS:
//   - mask-mode detect (16 KB scan, L2-served): int32 0/1 -> 0;
//     f32 0.0/1.0 -> 1; else bytes -> 2.
//   - barrier-free cumsum: per-thread serial over E=Tin/256 tokens, wave
//     shfl_up scan of thread sums, cross-wave offsets via 4 LDS partials.
//   - amp / inv_sigma per token.
// Block x==0 persists center/amp/inv to global for kernels 2-3.
// Then the denom chunk: per t, window search + exp-sum -> inv_den, lo, cnt.
// ---------------------------------------------------------------------------
__global__ __launch_bounds__(256) void denom_prep_k(
        const float* __restrict__ duration, const float* __restrict__ sigma,
        const void* __restrict__ mask,
        float* __restrict__ center, float* __restrict__ amp,
        float* __restrict__ inv_sigma, float* __restrict__ inv_den,
        int* __restrict__ lo_out, int* __restrict__ cnt_out,
        int B, int Tin, int Tout) {
    __shared__ float sc[1024], sa[1024], si[1024];
    __shared__ float s_wsum[4];
    __shared__ int s_not[2];
    int b = blockIdx.y, tid = threadIdx.x;
    if (tid < 2) s_not[tid] = 0;
    __syncthreads();
    {   // mask-mode detect over first B*Tin/4 words (min size over modes)
        const unsigned int* mw = (const unsigned int*)mask;
        int nwords = (B * Tin) >> 2;
        int nI = 0, nF = 0;
        for (int k = tid; k < nwords; k += 256) {
            unsigned int w = mw[k];
            nI |= (w != 0u && w != 1u);
            nF |= (w != 0u && w != 0x3F800000u);
        }
        if (nI) atomicOr(&s_not[0], 1);
        if (nF) atomicOr(&s_not[1], 1);
    }
    // ---- barrier-free row scan ----
    int E = Tin >> 8;                     // tokens per thread (2 for Tin=512)
    int base = tid * E;
    float x[8];                           // supports Tin up to 2048
    float tsum = 0.0f;
    const float* drow = duration + (size_t)b * Tin;
    for (int e = 0; e < E; ++e) { x[e] = drow[base + e]; tsum += x[e]; }
    float isc = tsum;                     // wave-inclusive scan of tsum
    int lane = tid & 63, wv = tid >> 6;
    #pragma unroll
    for (int d = 1; d < 64; d <<= 1) {
        float v = __shfl_up(isc, d, 64);
        if (lane >= d) isc += v;
    }
    if (lane == 63) s_wsum[wv] = isc;
    __syncthreads();                      // also fences s_not (atomicOrs above)
    float excl = isc - tsum;
    for (int w2 = 0; w2 < wv; ++w2) excl += s_wsum[w2];
    int mode = s_not[0] ? (s_not[1] ? 2 : 1) : 0;
    float run = excl;
    for (int e = 0; e < E; ++e) {
        float c = run + 0.5f * x[e];      // incl-cumsum - 0.5*d
        run += x[e];
        int i = base + e;
        size_t gi = (size_t)b * Tin + i;
        bool m;
        if (mode == 0)      m = ((const int*)mask)[gi] != 0;
        else if (mode == 1) m = ((const float*)mask)[gi] != 0.0f;
        else                m = ((const unsigned char*)mask)[gi] != 0;
        float sg = sigma[gi];
        float a  = m ? 0.0f : __expf(-__logf(sg) - HALF_LOG_2PI);
        float is = 1.0f / sg;
        sc[i] = c; sa[i] = a; si[i] = is;
        if (blockIdx.x == 0) { center[gi] = c; amp[gi] = a; inv_sigma[gi] = is; }
    }
    __syncthreads();
    // ---- denom chunk ----
    int t = blockIdx.x * 256 + tid;
    if (t >= Tout) return;
    float tf = (float)t;
    int lo = 0, hi = Tin;
    while (lo < hi) {                     // first i with center >= t - WIN
        int mid = (lo + hi) >> 1;
        if (sc[mid] < tf - WIN) lo = mid + 1; else hi = mid;
    }
    float sum = 0.0f;
    int i = lo;
    for (; i < Tin; ++i) {
        float cc = sc[i];
        if (cc > tf + WIN) break;
        float z = (tf - cc) * si[i];
        sum += sa[i] * __expf(-0.5f * z * z);
    }
    size_t g = (size_t)b * Tout + t;
    inv_den[g] = 1.0f / (sum + 1e-8f);
    lo_out[g]  = lo;
    cnt_out[g] = i - lo;
}

// ---------------------------------------------------------------------------
// Kernel 2: attn rows, 4 rows of one b per block (amortizes setup + iden L2
// reads). Coalesced nontemporal f32x4 writes; zeros outside +/-WIN window.
// ---------------------------------------------------------------------------
__global__ __launch_bounds__(256) void attn_k(
        const float* __restrict__ center, const float* __restrict__ amp,
        const float* __restrict__ inv_sigma, const float* __restrict__ inv_den,
        float* __restrict__ attn, int Tin, int Tout) {
    int q   = blockIdx.x;
    int rpb = Tin >> 2;                   // row-quads per batch
    int b   = q / rpb;
    int i0  = (q - b * rpb) * 4;
    const float* iden = inv_den + (size_t)b * Tout;
    int tid = threadIdx.x;
    #pragma unroll
    for (int rr = 0; rr < 4; ++rr) {
        int bi = b * Tin + i0 + rr;
        float c = center[bi], a = amp[bi], inv = inv_sigma[bi];
        float* row = attn + (size_t)bi * Tout;
        for (int t4 = tid * 4; t4 < Tout; t4 += 256 * 4) {
            f32x4 rv;
            if ((float)(t4 + 3) < c - WIN || (float)t4 > c + WIN) {
                rv = (f32x4)0.0f;
            } else {
                #pragma unroll
                for (int j = 0; j < 4; ++j) {
                    float dlt = (float)(t4 + j) - c;
                    if (fabsf(dlt) < WIN) {
                        float z = dlt * inv;
                        rv[j] = a * __expf(-0.5f * z * z) * iden[t4 + j];
                    } else rv[j] = 0.0f;
                }
            }
            __builtin_nontemporal_store(rv, (f32x4*)(row + t4));
        }
    }
}

// ---------------------------------------------------------------------------
// Kernel 3: upsampled[b,t,d] = sum_w attn[b,lo+w,t] * memory[b,lo+w,d].
// Block = (b, TILE_T-frame tile); 256 threads over D. Weights staged in LDS
// (f32x4 broadcast reads); memory rows read coalesced, reused TILE_T ways;
// XCD-chunk swizzle keeps ~4 b's (2 MB) per XCD L2.
// ---------------------------------------------------------------------------
__global__ __launch_bounds__(256) void upsample_k(
        const float* __restrict__ mem, const float* __restrict__ center,
        const float* __restrict__ amp, const float* __restrict__ inv_sigma,
        const float* __restrict__ inv_den, const int* __restrict__ lo_ws,
        const int* __restrict__ cnt_ws, float* __restrict__ out,
        int Tin, int Tout, int D) {
    __shared__ __align__(16) float w_s[TILE_T][128];
    __shared__ float s_iden[TILE_T];
    __shared__ int s_lo, s_cnt;
    int nwg = gridDim.x;
    int wid = blockIdx.x;
    int work = wid;
    if ((nwg & 7) == 0) {                 // XCD-chunked swizzle (8 XCDs)
        int chunk = nwg >> 3;
        work = (wid & 7) * chunk + (wid >> 3);
    }
    int tpb = Tout / TILE_T;
    int b   = work / tpb;
    int t0  = (work - b * tpb) * TILE_T;
    int tid = threadIdx.x;
    if (tid == 0) {
        size_t g0 = (size_t)b * Tout + t0;
        size_t g1 = g0 + (TILE_T - 1);
        int lo0 = lo_ws[g0];
        int cnt = lo_ws[g1] + cnt_ws[g1] - lo0;
        s_lo  = lo0;
        s_cnt = cnt > 128 ? 128 : cnt;    // mathematically <= ~81 (spacing>=1)
    }
    if (tid < TILE_T) s_iden[tid] = inv_den[(size_t)b * Tout + t0 + tid];
    __syncthreads();
    int lo0 = s_lo, wcnt = s_cnt;
    #pragma unroll
    for (int rep = 0; rep < (TILE_T * 128) / 256; ++rep) {
        int id = tid + rep * 256;
        int f = id >> 7, w = id & 127;
        float wgt = 0.0f;
        int i = lo0 + w;
        if (w < wcnt && i < Tin) {
            size_t gi = (size_t)b * Tin + i;
            float dlt = (float)(t0 + f) - center[gi];
            if (fabsf(dlt) < WIN) {
                float z = dlt * inv_sigma[gi];
                wgt = amp[gi] * __expf(-0.5f * z * z) * s_iden[f];
            }
        }
        w_s[f][w] = wgt;
    }
    __syncthreads();
    for (int d = tid; d < D; d += 256) {
        float acc[TILE_T];
        #pragma unroll
        for (int f = 0; f < TILE_T; ++f) acc[f] = 0.0f;
        const float* mrow = mem + ((size_t)b * Tin + lo0) * D + d;
        int w4 = wcnt & ~3;
        for (int w = 0; w < w4; w += 4) {
            float m0 = mrow[(size_t)(w + 0) * D];
            float m1 = mrow[(size_t)(w + 1) * D];
            float m2 = mrow[(size_t)(w + 2) * D];
            float m3 = mrow[(size_t)(w + 3) * D];
            #pragma unroll
            for (int f = 0; f < TILE_T; ++f) {
                f32x4 wv = *(const f32x4*)&w_s[f][w];   // LDS broadcast b128
                acc[f] += wv.x * m0 + wv.y * m1 + wv.z * m2 + wv.w * m3;
            }
        }
        for (int w = w4; w < wcnt; ++w) {
            float m0 = mrow[(size_t)w * D];
            #pragma unroll
            for (int f = 0; f < TILE_T; ++f) acc[f] += w_s[f][w] * m0;
        }
        float* orow = out + ((size_t)b * Tout + t0) * D + d;
        #pragma unroll
        for (int f = 0; f < TILE_T; ++f)
            __builtin_nontemporal_store(acc[f], orow + (size_t)f * D);
    }
}

extern "C" void kernel_launch(void* const* d_in, const int* in_sizes, int n_in,
                              void* d_out, int out_size, void* d_ws, size_t ws_size,
                              hipStream_t stream) {
    const float* memory   = (const float*)d_in[0];
    const float* duration = (const float*)d_in[1];
    const float* sigma    = (const float*)d_in[2];
    const void*  mask     = d_in[4];          // d_in[3]=output_lengths (unused)

    int B    = in_sizes[3];
    int Tin  = in_sizes[1] / B;
    int D    = in_sizes[0] / (B * Tin);
    int Tout = out_size / (B * (D + Tin));

    float* out_up   = (float*)d_out;
    float* out_attn = out_up + (size_t)B * Tout * D;

    // workspace layout
    float* center = (float*)d_ws;
    float* amp    = center + (size_t)B * Tin;
    float* inv    = amp    + (size_t)B * Tin;
    float* iden   = inv    + (size_t)B * Tin;
    int*   lo     = (int*)(iden + (size_t)B * Tout);
    int*   cnt    = lo + (size_t)B * Tout;

    denom_prep_k<<<dim3((Tout + 255) / 256, B), 256, 0, stream>>>(
        duration, sigma, mask, center, amp, inv, iden, lo, cnt,
        B, Tin, Tout);
    attn_k<<<(B * Tin) / 4, 256, 0, stream>>>(center, amp, inv, iden,
                                              out_attn, Tin, Tout);
    upsample_k<<<(B * Tout) / TILE_T, 256, 0, stream>>>(
        memory, center, amp, inv, iden, lo, cnt, out_up, Tin, Tout, D);
}